// Round 10
// baseline (524.973 us; speedup 1.0000x reference)
//
#include <hip/hip_runtime.h>
#include <stdint.h>

#define N_NODES 16384
#define NHN 4096
#define DIM 1024
#define K2D 2048
#define E_TOT 65536
#define E_HH 8192
#define E_OO 40960
// type boundaries: [0,8192) hh, [8192,49152) oo, [49152,65536) ho

typedef __attribute__((ext_vector_type(4))) float f32x4;
typedef __attribute__((ext_vector_type(8))) short s16x8;
typedef __attribute__((ext_vector_type(2))) long l64x2;   // 16B: two fp8 MFMA operands

static __device__ __forceinline__ unsigned short f2bf(float f) {
  union { float f; unsigned u; } v; v.f = f;
  unsigned r = v.u + 0x7FFF + ((v.u >> 16) & 1);
  return (unsigned short)(r >> 16);
}
static __device__ __forceinline__ float bf2f(unsigned short u) {
  union { unsigned u; float f; } v; v.u = ((unsigned)u) << 16;
  return v.f;
}

// fp8 granule permutation: within each 64B K-block, logical granule
// g = kk*4+quad (8B) is STORED at position quad*2+kk. One b128 read at
// stored chunk = quad then yields both kk operands for that quad.
static __device__ __forceinline__ int fp8pos(int k) {   // k: logical byte in row
  int gl = (k >> 3) & 7;
  return (k & ~63) + ((((gl & 3) << 1) | (gl >> 2)) << 3) + (k & 7);
}

// async 16B global -> LDS. LDS side must be wave-uniform base + lane*16;
// global side may be per-lane (gather ok).
static __device__ __forceinline__ void async16(const void* g, void* l) {
  __builtin_amdgcn_global_load_lds(
      (const __attribute__((address_space(1))) unsigned int*)g,
      (__attribute__((address_space(3))) unsigned int*)l,
      16, 0, 0);
}

// ---- K0a: cast n_f fp32 -> bf16 into A_node[n][0..1024) (row stride 2048)
//      AND fp8 e4m3 (granule-permuted) into the dead z-half scratch:
//      bytes [n*4096+2048, n*4096+3072). K1 consumes it before K3 rewrites z.
__global__ __launch_bounds__(256) void k_cast_nf(const float* __restrict__ nf,
                                                 unsigned short* __restrict__ A,
                                                 unsigned char* __restrict__ A8) {
  int i = blockIdx.x * 256 + threadIdx.x;   // 4194304 float4 groups
  float4 v = ((const float4*)nf)[i];
  int n = i >> 8;
  int k = (i & 255) << 2;
  ushort4 o;
  o.x = f2bf(v.x); o.y = f2bf(v.y); o.z = f2bf(v.z); o.w = f2bf(v.w);
  *(ushort4*)(A + (size_t)n * K2D + k) = o;
  int p = __builtin_amdgcn_cvt_pk_fp8_f32(v.x, v.y, 0, false);   // bytes 0,1
  p = __builtin_amdgcn_cvt_pk_fp8_f32(v.z, v.w, p, true);        // bytes 2,3
  *(int*)(A8 + (size_t)n * 4096 + fp8pos(k)) = p;   // k&7 in {0,4}: stays in-granule
}

// ---- K0b: transpose W [2048][1024] fp32. Edge matrices (w<3): fp8(64*W),
//      granule-permuted, into Wt8. Node matrices (w>=3): bf16 into WtN. ----
__global__ __launch_bounds__(256) void k_transpose(const float* __restrict__ W0,
                                                   const float* __restrict__ W1,
                                                   const float* __restrict__ W2,
                                                   const float* __restrict__ W3,
                                                   const float* __restrict__ W4,
                                                   unsigned char* __restrict__ Wt8,
                                                   unsigned short* __restrict__ WtN) {
  int bid = blockIdx.x;
  int w = bid >> 11;
  int tt = bid & 2047;
  int kt = tt & 63, jt = tt >> 6;
  const float* W = (w == 0) ? W0 : (w == 1) ? W1 : (w == 2) ? W2 : (w == 3) ? W3 : W4;
  __shared__ float s[32][33];
  int c = threadIdx.x & 31, r0 = threadIdx.x >> 5;
#pragma unroll
  for (int i = 0; i < 4; ++i) {
    int r = r0 + i * 8;
    s[r][c] = W[(size_t)(kt * 32 + r) * DIM + jt * 32 + c];
  }
  __syncthreads();
  if (w < 3) {
    unsigned char* dst8 = Wt8 + (size_t)w * (DIM * K2D);
#pragma unroll
    for (int i = 0; i < 4; ++i) {
      int r = r0 + i * 8;
      int q = __builtin_amdgcn_cvt_pk_fp8_f32(s[c][r] * 64.0f, 0.0f, 0, false);
      dst8[(size_t)(jt * 32 + r) * K2D + fp8pos(kt * 32 + c)] = (unsigned char)(q & 0xff);
    }
  } else {
    unsigned short* dst = WtN + (size_t)(w - 3) * (DIM * K2D);
#pragma unroll
    for (int i = 0; i < 4; ++i) {
      int r = r0 + i * 8;
      dst[(size_t)(jt * 32 + r) * K2D + kt * 32 + c] = f2bf(s[c][r]);
    }
  }
}

// ---- K1: fused edge MLP + attention logit, FP8 e4m3, conflict-free LDS,
// 3 blocks/CU (fp8 LDS = 36KB -> 3x36=108<160KB; VGPR 100 < 170 cap, no spill).
// Structure = round-0 schedule (stage -> sync -> compute -> sync, 64 edges x
// 512 cols, BK=64, 256 thr = 4 waves). Cross-block overlap is the proven
// mechanism (R0 vs R1/R2); 3 independent pipelines/CU instead of 2.
// LDS: 16B chunk XOR c ^ ((r>>1)&3) (async16-compatible); storage is
// granule-permuted so reader does ONE ds_read_b128 at chunk quad^((l16>>1)&3)
// per fragment, covering both kk halves (verified conflict-free, R9: 0).
// W stored as fp8(64*W); epilogue multiplies acc by 1/64 before bias.
__global__ __launch_bounds__(256, 3) void k_edge_logit(
    const unsigned char* __restrict__ A8,      // fp8 (permuted), row stride 4096 B
    const unsigned char* __restrict__ W8_all,  // 3 x [1024][2048] fp8 (x64, permuted)
    const float* __restrict__ b_hh, const float* __restrict__ b_oo, const float* __restrict__ b_ho,
    const float* __restrict__ Wa,
    const int* __restrict__ esrc, const int* __restrict__ edst,
    float* __restrict__ logit) {
  const int t = threadIdx.x;
  const int half = blockIdx.x;         // 0..1 : 512-col half
  const int e0 = blockIdx.y * 64;
  const unsigned char* W8;
  const float* bias;
  if (e0 < E_HH)              { W8 = W8_all;                 bias = b_hh; }
  else if (e0 < E_HH + E_OO)  { W8 = W8_all + 1 * 2097152;   bias = b_oo; }
  else                        { W8 = W8_all + 2 * 2097152;   bias = b_ho; }
  const int n0 = half * 512;

  __shared__ __align__(16) unsigned char sA[64 * 64];    //  4 KB
  __shared__ __align__(16) unsigned char sB[512 * 64];   // 32 KB

  const int r0 = t >> 2;               // 0..63 staged row
  const int c0 = t & 3;                // chunk slot
  const int cg = (c0 ^ ((r0 >> 1) & 3)) * 16;  // swizzled global chunk (bytes)
  const int s0 = esrc[e0 + r0], d0 = edst[e0 + r0];
  const unsigned char* pS = A8 + (size_t)s0 * 4096 + cg;
  const unsigned char* pD = A8 + (size_t)d0 * 4096 + cg;
  const unsigned char* pB = W8 + (size_t)(n0 + r0) * K2D + cg;   // + p*64 rows
  unsigned char* lA = sA + t * 16;
  unsigned char* lB = sB + t * 16;     // + p*4096

  const int lane = t & 63, wid = t >> 6;
  const int quad = lane >> 4, l16 = lane & 15;
  const int cs = (quad ^ ((l16 >> 1) & 3)) << 4;   // de-swizzled chunk byte

  f32x4 acc[4][8];
#pragma unroll
  for (int a = 0; a < 4; ++a)
#pragma unroll
    for (int b = 0; b < 8; ++b) acc[a][b] = (f32x4){0.f, 0.f, 0.f, 0.f};

#pragma unroll 1
  for (int k0 = 0; k0 < K2D; k0 += 64) {
    const unsigned char* a = (k0 < 1024) ? (pS + k0) : (pD + (k0 - 1024));
    async16(a, lA);
#pragma unroll
    for (int p = 0; p < 8; ++p)
      async16(pB + (size_t)p * (64 * K2D) + k0, lB + p * 4096);
    __syncthreads();
    {
      l64x2 af[4], bfr[8];
#pragma unroll
      for (int mt = 0; mt < 4; ++mt)
        af[mt] = *(const l64x2*)(sA + (mt * 16 + l16) * 64 + cs);
#pragma unroll
      for (int nt = 0; nt < 8; ++nt)
        bfr[nt] = *(const l64x2*)(sB + (wid * 128 + nt * 16 + l16) * 64 + cs);
#pragma unroll
      for (int mt = 0; mt < 4; ++mt)
#pragma unroll
        for (int nt = 0; nt < 8; ++nt)
          acc[mt][nt] = __builtin_amdgcn_mfma_f32_16x16x32_fp8_fp8(af[mt].x, bfr[nt].x, acc[mt][nt], 0, 0, 0);
#pragma unroll
      for (int mt = 0; mt < 4; ++mt)
#pragma unroll
        for (int nt = 0; nt < 8; ++nt)
          acc[mt][nt] = __builtin_amdgcn_mfma_f32_16x16x32_fp8_fp8(af[mt].y, bfr[nt].y, acc[mt][nt], 0, 0, 0);
    }
    __syncthreads();
  }

  // epilogue: (acc/64) + bias, relu, *Wa, reduce over this wave's 128 cols
  float rowsum[4][4];
#pragma unroll
  for (int a = 0; a < 4; ++a)
#pragma unroll
    for (int b = 0; b < 4; ++b) rowsum[a][b] = 0.f;
#pragma unroll
  for (int nt = 0; nt < 8; ++nt) {
    int j = n0 + wid * 128 + nt * 16 + l16;
    float bj = bias[j], wj = Wa[j];
#pragma unroll
    for (int mt = 0; mt < 4; ++mt)
#pragma unroll
      for (int r = 0; r < 4; ++r) {
        float v = acc[mt][nt][r] * 0.015625f + bj;
        v = v > 0.f ? v : 0.f;
        rowsum[mt][r] += v * wj;
      }
  }
#pragma unroll
  for (int mt = 0; mt < 4; ++mt)
#pragma unroll
    for (int r = 0; r < 4; ++r) {
      float s = rowsum[mt][r];
      s += __shfl_xor(s, 1);
      s += __shfl_xor(s, 2);
      s += __shfl_xor(s, 4);
      s += __shfl_xor(s, 8);
      if (l16 == 0) atomicAdd(&logit[e0 + mt * 16 + quad * 4 + r], s);
    }
}

// ---- K2: CSR build ----
__global__ __launch_bounds__(256) void k_count(const int* __restrict__ edst, int* __restrict__ counts) {
  int e = blockIdx.x * 256 + threadIdx.x;
  atomicAdd(&counts[edst[e]], 1);
}

__global__ __launch_bounds__(1024) void k_scan(const int* __restrict__ counts,
                                               int* __restrict__ offsets,
                                               int* __restrict__ cursor) {
  __shared__ int sT[1024];
  int t = threadIdx.x;
  int base = t * 16;
  int loc[16];
  int s = 0;
#pragma unroll
  for (int i = 0; i < 16; ++i) { loc[i] = s; s += counts[base + i]; }
  sT[t] = s;
  __syncthreads();
  for (int off = 1; off < 1024; off <<= 1) {
    int v = (t >= off) ? sT[t - off] : 0;
    __syncthreads();
    sT[t] += v;
    __syncthreads();
  }
  int excl = sT[t] - s;
#pragma unroll
  for (int i = 0; i < 16; ++i) {
    int o = excl + loc[i];
    offsets[base + i] = o;
    cursor[base + i] = o;
  }
  if (t == 1023) offsets[N_NODES] = sT[1023];
}

__global__ __launch_bounds__(256) void k_fill(const int* __restrict__ edst,
                                              int* __restrict__ cursor,
                                              int* __restrict__ eord) {
  int e = blockIdx.x * 256 + threadIdx.x;
  int p = atomicAdd(&cursor[edst[e]], 1);
  eord[p] = e;
}

// ---- K3: per-node softmax + weighted aggregation -> z half of A_node ----
// (overwrites the fp8 scratch; K1 has already consumed it)
__global__ __launch_bounds__(256) void k_aggregate(const int* __restrict__ offsets,
                                                   const int* __restrict__ eord,
                                                   const float* __restrict__ logit,
                                                   const int* __restrict__ esrc,
                                                   unsigned short* __restrict__ A) {
  int n = blockIdx.x, t = threadIdx.x;
  int off = offsets[n], end = offsets[n + 1];
  float a0 = 0.f, a1 = 0.f, a2 = 0.f, a3 = 0.f;
  if (end > off) {
    float den = 0.f;
    for (int i = off; i < end; ++i) den += __expf(logit[eord[i]]);
    float rden = 1.0f / den;
    for (int i = off; i < end; ++i) {
      int e = eord[i];
      float al = __expf(logit[e]) * rden;
      int s = esrc[e];
      ushort4 v = *(const ushort4*)(A + (size_t)s * K2D + t * 4);
      a0 += al * bf2f(v.x);
      a1 += al * bf2f(v.y);
      a2 += al * bf2f(v.z);
      a3 += al * bf2f(v.w);
    }
  }
  ushort4 o;
  o.x = f2bf(a0); o.y = f2bf(a1); o.z = f2bf(a2); o.w = f2bf(a3);
  *(ushort4*)(A + (size_t)n * K2D + DIM + t * 4) = o;
}

// ---- K4: node MLP GEMM (bf16, UNCHANGED round-0 verified), tile 64 x 512 ----
__global__ __launch_bounds__(256, 2) void k_node_gemm(
    const unsigned short* __restrict__ A,
    const unsigned short* __restrict__ Wt_hn, const unsigned short* __restrict__ Wt_on,
    const float* __restrict__ b_hn, const float* __restrict__ b_on,
    float* __restrict__ out) {
  const int t = threadIdx.x;
  const int half = blockIdx.x;
  const int m0 = blockIdx.y * 64;
  const unsigned short* Wt = (m0 < NHN) ? Wt_hn : Wt_on;
  const float* bias = (m0 < NHN) ? b_hn : b_on;
  const int n0 = half * 512;

  __shared__ __align__(16) unsigned short sA[64 * 64];
  __shared__ __align__(16) unsigned short sB[512 * 64];

  const int row0 = t >> 3;
  const int cg = ((t & 7) ^ (row0 & 7)) * 8;
  const unsigned short* pA0 = A + (size_t)(m0 + row0) * K2D + cg;
  const unsigned short* pB0 = Wt + (size_t)(n0 + row0) * K2D + cg;
  unsigned short* lA0 = sA + t * 8;
  unsigned short* lA1 = sA + (256 + t) * 8;
  unsigned short* lB0 = sB + t * 8;

  const int lane = t & 63, wid = t >> 6;
  const int quad = lane >> 4, l16 = lane & 15;

  f32x4 acc[4][8];
#pragma unroll
  for (int a = 0; a < 4; ++a)
#pragma unroll
    for (int b = 0; b < 8; ++b) acc[a][b] = (f32x4){0.f, 0.f, 0.f, 0.f};

#pragma unroll 1
  for (int k0 = 0; k0 < K2D; k0 += 64) {
    async16(pA0 + k0, lA0);
    async16(pA0 + (size_t)32 * K2D + k0, lA1);
#pragma unroll
    for (int p = 0; p < 16; ++p)
      async16(pB0 + (size_t)p * (32 * K2D) + k0, lB0 + p * 2048);
    __syncthreads();
#pragma unroll 1
    for (int kk = 0; kk < 2; ++kk) {
      const int pc = ((kk * 4 + quad) ^ (l16 & 7)) * 8;
      s16x8 af[4], bfr[8];
#pragma unroll
      for (int mt = 0; mt < 4; ++mt)
        af[mt] = *(const s16x8*)(sA + (mt * 16 + l16) * 64 + pc);
#pragma unroll
      for (int nt = 0; nt < 8; ++nt)
        bfr[nt] = *(const s16x8*)(sB + (wid * 128 + nt * 16 + l16) * 64 + pc);
#pragma unroll
      for (int mt = 0; mt < 4; ++mt)
#pragma unroll
        for (int nt = 0; nt < 8; ++nt)
          acc[mt][nt] = __builtin_amdgcn_mfma_f32_16x16x32_bf16(af[mt], bfr[nt], acc[mt][nt], 0, 0, 0);
    }
    __syncthreads();
  }
#pragma unroll
  for (int nt = 0; nt < 8; ++nt) {
    int jl = wid * 128 + nt * 16 + l16;
    float bj = bias[n0 + jl];
    int j = n0 + jl;
#pragma unroll
    for (int mt = 0; mt < 4; ++mt)
#pragma unroll
      for (int r = 0; r < 4; ++r) {
        float v = acc[mt][nt][r] + bj;
        v = v > 0.f ? v : 0.f;
        int m = m0 + mt * 16 + quad * 4 + r;
        out[(size_t)m * DIM + j] = v;
      }
  }
}

// ---- workspace layout (bytes) — UNCHANGED ENVELOPE (ends 88801536) ----
//   A_node : 0          .. 67108864   [16384][2048] bf16
//            (fp8 A8 scratch lives in bytes [n*4096+2048, n*4096+3072) of
//             each row — the z-half — consumed by K1 before K3 rewrites it)
//   Wt8    : 67108864   .. 73400320   3 x [1024][2048] fp8 (x64: hh, oo, ho)
//   WtN    : 73400320   .. 81788928   2 x [1024][2048] bf16 (hn, on)
//   logit  : 88080384   .. 88342528   [65536] f32
//   counts : 88342528   .. 88408064   [16384] i32
//   offsets: 88408064   .. 88473856   [16385] i32 (+pad)
//   cursor : 88473856   .. 88539392   [16384] i32
//   eord   : 88539392   .. 88801536   [65536] i32
extern "C" void kernel_launch(void* const* d_in, const int* in_sizes, int n_in,
                              void* d_out, int out_size, void* d_ws, size_t ws_size,
                              hipStream_t stream) {
  const float* n_f  = (const float*)d_in[0];
  const float* W_hh = (const float*)d_in[1];
  const float* b_hh = (const float*)d_in[2];
  const float* W_oo = (const float*)d_in[3];
  const float* b_oo = (const float*)d_in[4];
  const float* W_ho = (const float*)d_in[5];
  const float* b_ho = (const float*)d_in[6];
  const float* W_a  = (const float*)d_in[7];
  // d_in[8] = b_a : dropped (uniform shift cancels in segment softmax)
  const float* W_hn = (const float*)d_in[9];
  const float* b_hn = (const float*)d_in[10];
  const float* W_on = (const float*)d_in[11];
  const float* b_on = (const float*)d_in[12];
  const int* esrc = (const int*)d_in[13];
  const int* edst = (const int*)d_in[14];
  float* out = (float*)d_out;

  char* ws = (char*)d_ws;
  unsigned short* A_node = (unsigned short*)(ws);
  unsigned char* A8      = (unsigned char*)(ws + 2048);      // row stride 4096 B (z-half scratch)
  unsigned char* Wt8     = (unsigned char*)(ws + 67108864);
  unsigned short* WtN    = (unsigned short*)(ws + 73400320);
  float* logit  = (float*)(ws + 88080384);
  int* counts   = (int*)(ws + 88342528);
  int* offsets  = (int*)(ws + 88408064);
  int* cursor   = (int*)(ws + 88473856);
  int* eord     = (int*)(ws + 88539392);

  hipMemsetAsync(ws + 88080384, 0, 262144 + 65536, stream);

  k_cast_nf<<<16384, 256, 0, stream>>>(n_f, A_node, A8);
  k_transpose<<<5 * 2048, 256, 0, stream>>>(W_hh, W_oo, W_ho, W_hn, W_on, Wt8, WtN);
  k_edge_logit<<<dim3(2, E_TOT / 64), 256, 0, stream>>>(A8, Wt8, b_hh, b_oo, b_ho, W_a, esrc, edst, logit);
  k_count<<<E_TOT / 256, 256, 0, stream>>>(edst, counts);
  k_scan<<<1, 1024, 0, stream>>>(counts, offsets, cursor);
  k_fill<<<E_TOT / 256, 256, 0, stream>>>(edst, cursor, eord);
  k_aggregate<<<N_NODES, 256, 0, stream>>>(offsets, eord, logit, esrc, A_node);
  k_node_gemm<<<dim3(2, N_NODES / 64), 256, 0, stream>>>(
      A_node, WtN, WtN + 2097152, b_hn, b_on, out);
}

// Round 11
// 452.502 us; speedup vs baseline: 1.1602x; 1.1602x over previous
//
#include <hip/hip_runtime.h>
#include <stdint.h>

#define N_NODES 16384
#define NHN 4096
#define DIM 1024
#define K2D 2048
#define E_TOT 65536
#define E_HH 8192
#define E_OO 40960
// type boundaries: [0,8192) hh, [8192,49152) oo, [49152,65536) ho

typedef __attribute__((ext_vector_type(4))) float f32x4;
typedef __attribute__((ext_vector_type(8))) short s16x8;
typedef __attribute__((ext_vector_type(4))) int i32x4;
typedef __attribute__((ext_vector_type(8))) int i32x8;

static __device__ __forceinline__ unsigned short f2bf(float f) {
  union { float f; unsigned u; } v; v.f = f;
  unsigned r = v.u + 0x7FFF + ((v.u >> 16) & 1);
  return (unsigned short)(r >> 16);
}
static __device__ __forceinline__ float bf2f(unsigned short u) {
  union { unsigned u; float f; } v; v.u = ((unsigned)u) << 16;
  return v.f;
}

// async 16B global -> LDS. LDS side must be wave-uniform base + lane*16;
// global side may be per-lane (gather ok).
static __device__ __forceinline__ void async16(const void* g, void* l) {
  __builtin_amdgcn_global_load_lds(
      (const __attribute__((address_space(1))) unsigned int*)g,
      (__attribute__((address_space(3))) unsigned int*)l,
      16, 0, 0);
}

// ---- K0a: cast n_f fp32 -> bf16 into A_node[n][0..1024) (row stride 2048)
//      AND fp8 e4m3 (LINEAR layout) into the dead z-half scratch:
//      bytes [n*4096+2048, n*4096+3072). K1 consumes it before K3 rewrites z.
__global__ __launch_bounds__(256) void k_cast_nf(const float* __restrict__ nf,
                                                 unsigned short* __restrict__ A,
                                                 unsigned char* __restrict__ A8) {
  int i = blockIdx.x * 256 + threadIdx.x;   // 4194304 float4 groups
  float4 v = ((const float4*)nf)[i];
  int n = i >> 8;
  int k = (i & 255) << 2;
  ushort4 o;
  o.x = f2bf(v.x); o.y = f2bf(v.y); o.z = f2bf(v.z); o.w = f2bf(v.w);
  *(ushort4*)(A + (size_t)n * K2D + k) = o;
  int p = __builtin_amdgcn_cvt_pk_fp8_f32(v.x, v.y, 0, false);   // bytes 0,1
  p = __builtin_amdgcn_cvt_pk_fp8_f32(v.z, v.w, p, true);        // bytes 2,3
  *(int*)(A8 + (size_t)n * 4096 + k) = p;   // A8 row stride 4096 B, linear
}

// ---- K0b: transpose W [2048][1024] fp32. Edge matrices (w<3): fp8(64*W),
//      LINEAR, into Wt8. Node matrices (w>=3): bf16 into WtN. ----
__global__ __launch_bounds__(256) void k_transpose(const float* __restrict__ W0,
                                                   const float* __restrict__ W1,
                                                   const float* __restrict__ W2,
                                                   const float* __restrict__ W3,
                                                   const float* __restrict__ W4,
                                                   unsigned char* __restrict__ Wt8,
                                                   unsigned short* __restrict__ WtN) {
  int bid = blockIdx.x;
  int w = bid >> 11;
  int tt = bid & 2047;
  int kt = tt & 63, jt = tt >> 6;
  const float* W = (w == 0) ? W0 : (w == 1) ? W1 : (w == 2) ? W2 : (w == 3) ? W3 : W4;
  __shared__ float s[32][33];
  int c = threadIdx.x & 31, r0 = threadIdx.x >> 5;
#pragma unroll
  for (int i = 0; i < 4; ++i) {
    int r = r0 + i * 8;
    s[r][c] = W[(size_t)(kt * 32 + r) * DIM + jt * 32 + c];
  }
  __syncthreads();
  if (w < 3) {
    unsigned char* dst8 = Wt8 + (size_t)w * (DIM * K2D);
#pragma unroll
    for (int i = 0; i < 4; ++i) {
      int r = r0 + i * 8;
      int q = __builtin_amdgcn_cvt_pk_fp8_f32(s[c][r] * 64.0f, 0.0f, 0, false);
      dst8[(size_t)(jt * 32 + r) * K2D + kt * 32 + c] = (unsigned char)(q & 0xff);
    }
  } else {
    unsigned short* dst = WtN + (size_t)(w - 3) * (DIM * K2D);
#pragma unroll
    for (int i = 0; i < 4; ++i) {
      int r = r0 + i * 8;
      dst[(size_t)(jt * 32 + r) * K2D + kt * 32 + c] = f2bf(s[c][r]);
    }
  }
}

// ---- K1: fused edge MLP + attention logit, MX-scaled FP8, K=128 per MFMA.
// mfma_scale_f32_16x16x128_f8f6f4 @ ~4661 TF (2.3x non-scaled fp8) -> MFMA
// issue floor 59us (was 134us = the R9 binding constraint, MfmaUtil 54.7%).
// Tile 64 edges x 512 cols, BK=128, 16 K-iters (barrier count halved), 256
// thr = 4 waves, LDS 8+64=72KB -> 2 blocks/CU, cross-block overlap as R0/R9.
// Scales = e8m0 127 (x1, replicated bytes so opsel moot); epilogue keeps /64.
// LDS swizzle: K4's proven-0-conflict 3-bit XOR on 16B chunks of 128B rows
// (slot = chunk ^ (row&7)); fragment = 32 contiguous bytes (k = quad*32+i)
// read as two b128 at chunks (2q)^(l16&7), (2q+1)^(l16&7).
__global__ __launch_bounds__(256, 2) void k_edge_logit(
    const unsigned char* __restrict__ A8,      // fp8 linear, row stride 4096 B
    const unsigned char* __restrict__ W8_all,  // 3 x [1024][2048] fp8 (x64)
    const float* __restrict__ b_hh, const float* __restrict__ b_oo, const float* __restrict__ b_ho,
    const float* __restrict__ Wa,
    const int* __restrict__ esrc, const int* __restrict__ edst,
    float* __restrict__ logit) {
  const int t = threadIdx.x;
  const int half = blockIdx.x;         // 0..1 : 512-col half
  const int e0 = blockIdx.y * 64;
  const unsigned char* W8;
  const float* bias;
  if (e0 < E_HH)              { W8 = W8_all;                 bias = b_hh; }
  else if (e0 < E_HH + E_OO)  { W8 = W8_all + 1 * 2097152;   bias = b_oo; }
  else                        { W8 = W8_all + 2 * 2097152;   bias = b_ho; }
  const int n0 = half * 512;

  __shared__ __align__(16) unsigned char sA[64 * 128];    //  8 KB
  __shared__ __align__(16) unsigned char sB[512 * 128];   // 64 KB

  const int l = t & 63, w = t >> 6;
  const int rr = l >> 3;                       // 0..7 : staged row within 8-row band
  const int goff = ((l & 7) ^ rr) * 16;        // swizzled 16B chunk within 128B slice

  const int ra = w * 8 + rr;                   // A rows 0..31 (issue0), +32 (issue1)
  const unsigned char* pS0 = A8 + (size_t)esrc[e0 + ra] * 4096 + goff;
  const unsigned char* pS1 = A8 + (size_t)esrc[e0 + ra + 32] * 4096 + goff;
  const unsigned char* pD0 = A8 + (size_t)edst[e0 + ra] * 4096 + goff;
  const unsigned char* pD1 = A8 + (size_t)edst[e0 + ra + 32] * 4096 + goff;
  const unsigned char* pB = W8 + (size_t)(n0 + w * 128 + rr) * K2D + goff;  // + p*8 rows
  unsigned char* lA = sA + w * 1024 + l * 16;  // issue1: +4096
  unsigned char* lB = sB + w * 16384 + l * 16; // + p*1024

  const int quad = l >> 4, l16 = l & 15;
  const int c0 = ((2 * quad) ^ (l16 & 7)) << 4;      // de-swizzled chunk bytes
  const int c1 = ((2 * quad + 1) ^ (l16 & 7)) << 4;

  f32x4 acc[4][8];
#pragma unroll
  for (int a = 0; a < 4; ++a)
#pragma unroll
    for (int b = 0; b < 8; ++b) acc[a][b] = (f32x4){0.f, 0.f, 0.f, 0.f};

#pragma unroll 1
  for (int it = 0; it < 16; ++it) {
    const int k0 = it * 128;
    const unsigned char* a0 = (k0 < 1024) ? (pS0 + k0) : (pD0 + (k0 - 1024));
    const unsigned char* a1 = (k0 < 1024) ? (pS1 + k0) : (pD1 + (k0 - 1024));
    async16(a0, lA);
    async16(a1, lA + 4096);
#pragma unroll
    for (int p = 0; p < 16; ++p)
      async16(pB + (size_t)p * (8 * K2D) + k0, lB + p * 1024);
    __syncthreads();
    {
      i32x8 af[4];
#pragma unroll
      for (int mt = 0; mt < 4; ++mt) {
        const unsigned char* ba = sA + (mt * 16 + l16) * 128;
        i32x4 x = *(const i32x4*)(ba + c0);
        i32x4 y = *(const i32x4*)(ba + c1);
        af[mt] = __builtin_shufflevector(x, y, 0, 1, 2, 3, 4, 5, 6, 7);
      }
#pragma unroll
      for (int nt = 0; nt < 8; ++nt) {
        const unsigned char* bb = sB + (size_t)(w * 128 + nt * 16 + l16) * 128;
        i32x4 x = *(const i32x4*)(bb + c0);
        i32x4 y = *(const i32x4*)(bb + c1);
        i32x8 bfv = __builtin_shufflevector(x, y, 0, 1, 2, 3, 4, 5, 6, 7);
#pragma unroll
        for (int mt = 0; mt < 4; ++mt)
          acc[mt][nt] = __builtin_amdgcn_mfma_scale_f32_16x16x128_f8f6f4(
              af[mt], bfv, acc[mt][nt], 0, 0, 0, 0x7F7F7F7Fu, 0, 0x7F7F7F7Fu);
      }
    }
    __syncthreads();
  }

  // epilogue: (acc/64) + bias, relu, *Wa, reduce over this wave's 128 cols
  float rowsum[4][4];
#pragma unroll
  for (int a = 0; a < 4; ++a)
#pragma unroll
    for (int b = 0; b < 4; ++b) rowsum[a][b] = 0.f;
#pragma unroll
  for (int nt = 0; nt < 8; ++nt) {
    int j = n0 + w * 128 + nt * 16 + l16;
    float bj = bias[j], wj = Wa[j];
#pragma unroll
    for (int mt = 0; mt < 4; ++mt)
#pragma unroll
      for (int r = 0; r < 4; ++r) {
        float v = acc[mt][nt][r] * 0.015625f + bj;
        v = v > 0.f ? v : 0.f;
        rowsum[mt][r] += v * wj;
      }
  }
#pragma unroll
  for (int mt = 0; mt < 4; ++mt)
#pragma unroll
    for (int r = 0; r < 4; ++r) {
      float s = rowsum[mt][r];
      s += __shfl_xor(s, 1);
      s += __shfl_xor(s, 2);
      s += __shfl_xor(s, 4);
      s += __shfl_xor(s, 8);
      if (l16 == 0) atomicAdd(&logit[e0 + mt * 16 + quad * 4 + r], s);
    }
}

// ---- K2: CSR build ----
__global__ __launch_bounds__(256) void k_count(const int* __restrict__ edst, int* __restrict__ counts) {
  int e = blockIdx.x * 256 + threadIdx.x;
  atomicAdd(&counts[edst[e]], 1);
}

__global__ __launch_bounds__(1024) void k_scan(const int* __restrict__ counts,
                                               int* __restrict__ offsets,
                                               int* __restrict__ cursor) {
  __shared__ int sT[1024];
  int t = threadIdx.x;
  int base = t * 16;
  int loc[16];
  int s = 0;
#pragma unroll
  for (int i = 0; i < 16; ++i) { loc[i] = s; s += counts[base + i]; }
  sT[t] = s;
  __syncthreads();
  for (int off = 1; off < 1024; off <<= 1) {
    int v = (t >= off) ? sT[t - off] : 0;
    __syncthreads();
    sT[t] += v;
    __syncthreads();
  }
  int excl = sT[t] - s;
#pragma unroll
  for (int i = 0; i < 16; ++i) {
    int o = excl + loc[i];
    offsets[base + i] = o;
    cursor[base + i] = o;
  }
  if (t == 1023) offsets[N_NODES] = sT[1023];
}

__global__ __launch_bounds__(256) void k_fill(const int* __restrict__ edst,
                                              int* __restrict__ cursor,
                                              int* __restrict__ eord) {
  int e = blockIdx.x * 256 + threadIdx.x;
  int p = atomicAdd(&cursor[edst[e]], 1);
  eord[p] = e;
}

// ---- K3: per-node softmax + weighted aggregation -> z half of A_node ----
// (overwrites the fp8 scratch; K1 has already consumed it)
__global__ __launch_bounds__(256) void k_aggregate(const int* __restrict__ offsets,
                                                   const int* __restrict__ eord,
                                                   const float* __restrict__ logit,
                                                   const int* __restrict__ esrc,
                                                   unsigned short* __restrict__ A) {
  int n = blockIdx.x, t = threadIdx.x;
  int off = offsets[n], end = offsets[n + 1];
  float a0 = 0.f, a1 = 0.f, a2 = 0.f, a3 = 0.f;
  if (end > off) {
    float den = 0.f;
    for (int i = off; i < end; ++i) den += __expf(logit[eord[i]]);
    float rden = 1.0f / den;
    for (int i = off; i < end; ++i) {
      int e = eord[i];
      float al = __expf(logit[e]) * rden;
      int s = esrc[e];
      ushort4 v = *(const ushort4*)(A + (size_t)s * K2D + t * 4);
      a0 += al * bf2f(v.x);
      a1 += al * bf2f(v.y);
      a2 += al * bf2f(v.z);
      a3 += al * bf2f(v.w);
    }
  }
  ushort4 o;
  o.x = f2bf(a0); o.y = f2bf(a1); o.z = f2bf(a2); o.w = f2bf(a3);
  *(ushort4*)(A + (size_t)n * K2D + DIM + t * 4) = o;
}

// ---- K4: node MLP GEMM (bf16, UNCHANGED round-0 verified), tile 64 x 512 ----
__global__ __launch_bounds__(256, 2) void k_node_gemm(
    const unsigned short* __restrict__ A,
    const unsigned short* __restrict__ Wt_hn, const unsigned short* __restrict__ Wt_on,
    const float* __restrict__ b_hn, const float* __restrict__ b_on,
    float* __restrict__ out) {
  const int t = threadIdx.x;
  const int half = blockIdx.x;
  const int m0 = blockIdx.y * 64;
  const unsigned short* Wt = (m0 < NHN) ? Wt_hn : Wt_on;
  const float* bias = (m0 < NHN) ? b_hn : b_on;
  const int n0 = half * 512;

  __shared__ __align__(16) unsigned short sA[64 * 64];
  __shared__ __align__(16) unsigned short sB[512 * 64];

  const int row0 = t >> 3;
  const int cg = ((t & 7) ^ (row0 & 7)) * 8;
  const unsigned short* pA0 = A + (size_t)(m0 + row0) * K2D + cg;
  const unsigned short* pB0 = Wt + (size_t)(n0 + row0) * K2D + cg;
  unsigned short* lA0 = sA + t * 8;
  unsigned short* lA1 = sA + (256 + t) * 8;
  unsigned short* lB0 = sB + t * 8;

  const int lane = t & 63, wid = t >> 6;
  const int quad = lane >> 4, l16 = lane & 15;

  f32x4 acc[4][8];
#pragma unroll
  for (int a = 0; a < 4; ++a)
#pragma unroll
    for (int b = 0; b < 8; ++b) acc[a][b] = (f32x4){0.f, 0.f, 0.f, 0.f};

#pragma unroll 1
  for (int k0 = 0; k0 < K2D; k0 += 64) {
    async16(pA0 + k0, lA0);
    async16(pA0 + (size_t)32 * K2D + k0, lA1);
#pragma unroll
    for (int p = 0; p < 16; ++p)
      async16(pB0 + (size_t)p * (32 * K2D) + k0, lB0 + p * 2048);
    __syncthreads();
#pragma unroll 1
    for (int kk = 0; kk < 2; ++kk) {
      const int pc = ((kk * 4 + quad) ^ (l16 & 7)) * 8;
      s16x8 af[4], bfr[8];
#pragma unroll
      for (int mt = 0; mt < 4; ++mt)
        af[mt] = *(const s16x8*)(sA + (mt * 16 + l16) * 64 + pc);
#pragma unroll
      for (int nt = 0; nt < 8; ++nt)
        bfr[nt] = *(const s16x8*)(sB + (wid * 128 + nt * 16 + l16) * 64 + pc);
#pragma unroll
      for (int mt = 0; mt < 4; ++mt)
#pragma unroll
        for (int nt = 0; nt < 8; ++nt)
          acc[mt][nt] = __builtin_amdgcn_mfma_f32_16x16x32_bf16(af[mt], bfr[nt], acc[mt][nt], 0, 0, 0);
    }
    __syncthreads();
  }
#pragma unroll
  for (int nt = 0; nt < 8; ++nt) {
    int jl = wid * 128 + nt * 16 + l16;
    float bj = bias[n0 + jl];
    int j = n0 + jl;
#pragma unroll
    for (int mt = 0; mt < 4; ++mt)
#pragma unroll
      for (int r = 0; r < 4; ++r) {
        float v = acc[mt][nt][r] + bj;
        v = v > 0.f ? v : 0.f;
        int m = m0 + mt * 16 + quad * 4 + r;
        out[(size_t)m * DIM + j] = v;
      }
  }
}

// ---- workspace layout (bytes) — UNCHANGED ENVELOPE (ends 88801536) ----
//   A_node : 0          .. 67108864   [16384][2048] bf16
//            (fp8 A8 scratch lives in bytes [n*4096+2048, n*4096+3072) of
//             each row — the z-half — consumed by K1 before K3 rewrites it)
//   Wt8    : 67108864   .. 73400320   3 x [1024][2048] fp8 (x64: hh, oo, ho)
//   WtN    : 73400320   .. 81788928   2 x [1024][2048] bf16 (hn, on)
//   logit  : 88080384   .. 88342528   [65536] f32
//   counts : 88342528   .. 88408064   [16384] i32
//   offsets: 88408064   .. 88473856   [16385] i32 (+pad)
//   cursor : 88473856   .. 88539392   [16384] i32
//   eord   : 88539392   .. 88801536   [65536] i32
extern "C" void kernel_launch(void* const* d_in, const int* in_sizes, int n_in,
                              void* d_out, int out_size, void* d_ws, size_t ws_size,
                              hipStream_t stream) {
  const float* n_f  = (const float*)d_in[0];
  const float* W_hh = (const float*)d_in[1];
  const float* b_hh = (const float*)d_in[2];
  const float* W_oo = (const float*)d_in[3];
  const float* b_oo = (const float*)d_in[4];
  const float* W_ho = (const float*)d_in[5];
  const float* b_ho = (const float*)d_in[6];
  const float* W_a  = (const float*)d_in[7];
  // d_in[8] = b_a : dropped (uniform shift cancels in segment softmax)
  const float* W_hn = (const float*)d_in[9];
  const float* b_hn = (const float*)d_in[10];
  const float* W_on = (const float*)d_in[11];
  const float* b_on = (const float*)d_in[12];
  const int* esrc = (const int*)d_in[13];
  const int* edst = (const int*)d_in[14];
  float* out = (float*)d_out;

  char* ws = (char*)d_ws;
  unsigned short* A_node = (unsigned short*)(ws);
  unsigned char* A8      = (unsigned char*)(ws + 2048);      // row stride 4096 B (z-half scratch)
  unsigned char* Wt8     = (unsigned char*)(ws + 67108864);
  unsigned short* WtN    = (unsigned short*)(ws + 73400320);
  float* logit  = (float*)(ws + 88080384);
  int* counts   = (int*)(ws + 88342528);
  int* offsets  = (int*)(ws + 88408064);
  int* cursor   = (int*)(ws + 88473856);
  int* eord     = (int*)(ws + 88539392);

  hipMemsetAsync(ws + 88080384, 0, 262144 + 65536, stream);

  k_cast_nf<<<16384, 256, 0, stream>>>(n_f, A_node, A8);
  k_transpose<<<5 * 2048, 256, 0, stream>>>(W_hh, W_oo, W_ho, W_hn, W_on, Wt8, WtN);
  k_edge_logit<<<dim3(2, E_TOT / 64), 256, 0, stream>>>(A8, Wt8, b_hh, b_oo, b_ho, W_a, esrc, edst, logit);
  k_count<<<E_TOT / 256, 256, 0, stream>>>(edst, counts);
  k_scan<<<1, 1024, 0, stream>>>(counts, offsets, cursor);
  k_fill<<<E_TOT / 256, 256, 0, stream>>>(edst, cursor, eord);
  k_aggregate<<<N_NODES, 256, 0, stream>>>(offsets, eord, logit, esrc, A_node);
  k_node_gemm<<<dim3(2, N_NODES / 64), 256, 0, stream>>>(
      A_node, WtN, WtN + 2097152, b_hn, b_on, out);
}

// Round 12
// 439.751 us; speedup vs baseline: 1.1938x; 1.0290x over previous
//
#include <hip/hip_runtime.h>
#include <stdint.h>

#define N_NODES 16384
#define NHN 4096
#define DIM 1024
#define K2D 2048
#define E_TOT 65536
#define E_HH 8192
#define E_OO 40960
// type boundaries: [0,8192) hh, [8192,49152) oo, [49152,65536) ho

typedef __attribute__((ext_vector_type(4))) float f32x4;
typedef __attribute__((ext_vector_type(8))) short s16x8;
typedef __attribute__((ext_vector_type(4))) int i32x4;
typedef __attribute__((ext_vector_type(8))) int i32x8;

static __device__ __forceinline__ unsigned short f2bf(float f) {
  union { float f; unsigned u; } v; v.f = f;
  unsigned r = v.u + 0x7FFF + ((v.u >> 16) & 1);
  return (unsigned short)(r >> 16);
}
static __device__ __forceinline__ float bf2f(unsigned short u) {
  union { unsigned u; float f; } v; v.u = ((unsigned)u) << 16;
  return v.f;
}

// async 16B global -> LDS. LDS side must be wave-uniform base + lane*16;
// global side may be per-lane (gather ok).
static __device__ __forceinline__ void async16(const void* g, void* l) {
  __builtin_amdgcn_global_load_lds(
      (const __attribute__((address_space(1))) unsigned int*)g,
      (__attribute__((address_space(3))) unsigned int*)l,
      16, 0, 0);
}

// ---- K0a: cast n_f fp32 -> bf16 into A_node[n][0..1024) (row stride 2048)
//      AND fp8 e4m3 (LINEAR layout) into the dead z-half scratch:
//      bytes [n*4096+2048, n*4096+3072). K1 consumes it before K3 rewrites z.
__global__ __launch_bounds__(256) void k_cast_nf(const float* __restrict__ nf,
                                                 unsigned short* __restrict__ A,
                                                 unsigned char* __restrict__ A8) {
  int i = blockIdx.x * 256 + threadIdx.x;   // 4194304 float4 groups
  float4 v = ((const float4*)nf)[i];
  int n = i >> 8;
  int k = (i & 255) << 2;
  ushort4 o;
  o.x = f2bf(v.x); o.y = f2bf(v.y); o.z = f2bf(v.z); o.w = f2bf(v.w);
  *(ushort4*)(A + (size_t)n * K2D + k) = o;
  int p = __builtin_amdgcn_cvt_pk_fp8_f32(v.x, v.y, 0, false);   // bytes 0,1
  p = __builtin_amdgcn_cvt_pk_fp8_f32(v.z, v.w, p, true);        // bytes 2,3
  *(int*)(A8 + (size_t)n * 4096 + k) = p;   // A8 row stride 4096 B, linear
}

// ---- K0b: transpose W [2048][1024] fp32. Edge matrices (w<3): fp8(64*W),
//      LINEAR, into Wt8. Node matrices (w>=3): bf16 into WtN. ----
__global__ __launch_bounds__(256) void k_transpose(const float* __restrict__ W0,
                                                   const float* __restrict__ W1,
                                                   const float* __restrict__ W2,
                                                   const float* __restrict__ W3,
                                                   const float* __restrict__ W4,
                                                   unsigned char* __restrict__ Wt8,
                                                   unsigned short* __restrict__ WtN) {
  int bid = blockIdx.x;
  int w = bid >> 11;
  int tt = bid & 2047;
  int kt = tt & 63, jt = tt >> 6;
  const float* W = (w == 0) ? W0 : (w == 1) ? W1 : (w == 2) ? W2 : (w == 3) ? W3 : W4;
  __shared__ float s[32][33];
  int c = threadIdx.x & 31, r0 = threadIdx.x >> 5;
#pragma unroll
  for (int i = 0; i < 4; ++i) {
    int r = r0 + i * 8;
    s[r][c] = W[(size_t)(kt * 32 + r) * DIM + jt * 32 + c];
  }
  __syncthreads();
  if (w < 3) {
    unsigned char* dst8 = Wt8 + (size_t)w * (DIM * K2D);
#pragma unroll
    for (int i = 0; i < 4; ++i) {
      int r = r0 + i * 8;
      int q = __builtin_amdgcn_cvt_pk_fp8_f32(s[c][r] * 64.0f, 0.0f, 0, false);
      dst8[(size_t)(jt * 32 + r) * K2D + kt * 32 + c] = (unsigned char)(q & 0xff);
    }
  } else {
    unsigned short* dst = WtN + (size_t)(w - 3) * (DIM * K2D);
#pragma unroll
    for (int i = 0; i < 4; ++i) {
      int r = r0 + i * 8;
      dst[(size_t)(jt * 32 + r) * K2D + kt * 32 + c] = f2bf(s[c][r]);
    }
  }
}

// ---- K1: fused edge MLP + attention logit, MX-scaled FP8, K=128 per MFMA.
// v2 tile: 128 edges x 256 cols (was 64x512) — halves staged bytes/FLOP:
// per-CU-iter staging 96KB (~1714 cyc L2) < MFMA demand (~2214 cyc) -> MFMA
// binding again (R11 was staging-bound: 147KB ~2633 cyc, MfmaUtil 37.6%).
// Total L2 staging 2.3GB -> 1.57GB. 256 thr = 4 waves in 2x2 grid, wave-tile
// 64x128 (acc[4][8] unchanged), BK=128, 16 iters, LDS 16+32=48KB -> 2
// blocks/CU, cross-block overlap (R0/R9/R11 mechanism) preserved.
// Swizzle: LDS[row][slot] = global[slot ^ (row&7)] (row&7 = rr for staged
// rows), reader fragment = 32B = two b128 at chunks (2q)^(l16&7), (2q+1)^...
// Scales = e8m0 127 (x1); W stored as fp8(64*W); epilogue /64 before bias.
__global__ __launch_bounds__(256, 2) void k_edge_logit(
    const unsigned char* __restrict__ A8,      // fp8 linear, row stride 4096 B
    const unsigned char* __restrict__ W8_all,  // 3 x [1024][2048] fp8 (x64)
    const float* __restrict__ b_hh, const float* __restrict__ b_oo, const float* __restrict__ b_ho,
    const float* __restrict__ Wa,
    const int* __restrict__ esrc, const int* __restrict__ edst,
    float* __restrict__ logit) {
  const int t = threadIdx.x;
  const int quarter = blockIdx.x;      // 0..3 : 256-col quarter
  const int e0 = blockIdx.y * 128;     // 512 e-blocks; type bounds /128 exact
  const unsigned char* W8;
  const float* bias;
  if (e0 < E_HH)              { W8 = W8_all;                 bias = b_hh; }
  else if (e0 < E_HH + E_OO)  { W8 = W8_all + 1 * 2097152;   bias = b_oo; }
  else                        { W8 = W8_all + 2 * 2097152;   bias = b_ho; }
  const int q0 = quarter * 256;

  __shared__ __align__(16) unsigned char sA[128 * 128];   // 16 KB
  __shared__ __align__(16) unsigned char sB[256 * 128];   // 32 KB

  const int l = t & 63, w = t >> 6;
  const int rr = l >> 3;                       // 0..7
  const int goff = ((l & 7) ^ rr) * 16;        // swizzled 16B chunk in 128B slice

  // A rows: j*32 + w*8 + rr  (j=0..3) — bijective onto 0..127
  const unsigned char* pS[4];
  const unsigned char* pD[4];
#pragma unroll
  for (int j = 0; j < 4; ++j) {
    int r = j * 32 + w * 8 + rr;
    pS[j] = A8 + (size_t)esrc[e0 + r] * 4096 + goff;
    pD[j] = A8 + (size_t)edst[e0 + r] * 4096 + goff;
  }
  // B cols: wave w stages its 64-col band: w*64 + p*8 + rr (p=0..7)
  const unsigned char* pB = W8 + (size_t)(q0 + w * 64 + rr) * K2D + goff;
  unsigned char* lA = sA + w * 1024 + l * 16;   // + j*4096
  unsigned char* lB = sB + w * 8192 + l * 16;   // + p*1024

  const int wr = w >> 1, wc = w & 1;            // wave -> 64-row x 128-col subtile
  const int quad = l >> 4, l16 = l & 15;
  const int c0 = ((2 * quad) ^ (l16 & 7)) << 4;      // de-swizzled chunk bytes
  const int c1 = ((2 * quad + 1) ^ (l16 & 7)) << 4;

  f32x4 acc[4][8];
#pragma unroll
  for (int a = 0; a < 4; ++a)
#pragma unroll
    for (int b = 0; b < 8; ++b) acc[a][b] = (f32x4){0.f, 0.f, 0.f, 0.f};

#pragma unroll 1
  for (int it = 0; it < 16; ++it) {
    const int k0 = it * 128;
    const bool ss = k0 < 1024;
    const int ko = ss ? k0 : (k0 - 1024);
#pragma unroll
    for (int j = 0; j < 4; ++j)
      async16((ss ? pS[j] : pD[j]) + ko, lA + j * 4096);
#pragma unroll
    for (int p = 0; p < 8; ++p)
      async16(pB + (size_t)p * (8 * K2D) + k0, lB + p * 1024);
    __syncthreads();
    {
      i32x8 af[4];
#pragma unroll
      for (int mt = 0; mt < 4; ++mt) {
        const unsigned char* ba = sA + (wr * 64 + mt * 16 + l16) * 128;
        i32x4 x = *(const i32x4*)(ba + c0);
        i32x4 y = *(const i32x4*)(ba + c1);
        af[mt] = __builtin_shufflevector(x, y, 0, 1, 2, 3, 4, 5, 6, 7);
      }
#pragma unroll
      for (int nt = 0; nt < 8; ++nt) {
        const unsigned char* bb = sB + (size_t)(wc * 128 + nt * 16 + l16) * 128;
        i32x4 x = *(const i32x4*)(bb + c0);
        i32x4 y = *(const i32x4*)(bb + c1);
        i32x8 bfv = __builtin_shufflevector(x, y, 0, 1, 2, 3, 4, 5, 6, 7);
#pragma unroll
        for (int mt = 0; mt < 4; ++mt)
          acc[mt][nt] = __builtin_amdgcn_mfma_scale_f32_16x16x128_f8f6f4(
              af[mt], bfv, acc[mt][nt], 0, 0, 0, 0x7F7F7F7Fu, 0, 0x7F7F7F7Fu);
      }
    }
    __syncthreads();
  }

  // epilogue: (acc/64) + bias, relu, *Wa, reduce over this wave's 128 cols
  float rowsum[4][4];
#pragma unroll
  for (int a = 0; a < 4; ++a)
#pragma unroll
    for (int b = 0; b < 4; ++b) rowsum[a][b] = 0.f;
#pragma unroll
  for (int nt = 0; nt < 8; ++nt) {
    int j = q0 + wc * 128 + nt * 16 + l16;
    float bj = bias[j], wj = Wa[j];
#pragma unroll
    for (int mt = 0; mt < 4; ++mt)
#pragma unroll
      for (int r = 0; r < 4; ++r) {
        float v = acc[mt][nt][r] * 0.015625f + bj;
        v = v > 0.f ? v : 0.f;
        rowsum[mt][r] += v * wj;
      }
  }
#pragma unroll
  for (int mt = 0; mt < 4; ++mt)
#pragma unroll
    for (int r = 0; r < 4; ++r) {
      float s = rowsum[mt][r];
      s += __shfl_xor(s, 1);
      s += __shfl_xor(s, 2);
      s += __shfl_xor(s, 4);
      s += __shfl_xor(s, 8);
      if (l16 == 0) atomicAdd(&logit[e0 + wr * 64 + mt * 16 + quad * 4 + r], s);
    }
}

// ---- K2: CSR build ----
__global__ __launch_bounds__(256) void k_count(const int* __restrict__ edst, int* __restrict__ counts) {
  int e = blockIdx.x * 256 + threadIdx.x;
  atomicAdd(&counts[edst[e]], 1);
}

__global__ __launch_bounds__(1024) void k_scan(const int* __restrict__ counts,
                                               int* __restrict__ offsets,
                                               int* __restrict__ cursor) {
  __shared__ int sT[1024];
  int t = threadIdx.x;
  int base = t * 16;
  int loc[16];
  int s = 0;
#pragma unroll
  for (int i = 0; i < 16; ++i) { loc[i] = s; s += counts[base + i]; }
  sT[t] = s;
  __syncthreads();
  for (int off = 1; off < 1024; off <<= 1) {
    int v = (t >= off) ? sT[t - off] : 0;
    __syncthreads();
    sT[t] += v;
    __syncthreads();
  }
  int excl = sT[t] - s;
#pragma unroll
  for (int i = 0; i < 16; ++i) {
    int o = excl + loc[i];
    offsets[base + i] = o;
    cursor[base + i] = o;
  }
  if (t == 1023) offsets[N_NODES] = sT[1023];
}

__global__ __launch_bounds__(256) void k_fill(const int* __restrict__ edst,
                                              int* __restrict__ cursor,
                                              int* __restrict__ eord) {
  int e = blockIdx.x * 256 + threadIdx.x;
  int p = atomicAdd(&cursor[edst[e]], 1);
  eord[p] = e;
}

// ---- K3: per-node softmax + weighted aggregation -> z half of A_node ----
// (overwrites the fp8 scratch; K1 has already consumed it)
__global__ __launch_bounds__(256) void k_aggregate(const int* __restrict__ offsets,
                                                   const int* __restrict__ eord,
                                                   const float* __restrict__ logit,
                                                   const int* __restrict__ esrc,
                                                   unsigned short* __restrict__ A) {
  int n = blockIdx.x, t = threadIdx.x;
  int off = offsets[n], end = offsets[n + 1];
  float a0 = 0.f, a1 = 0.f, a2 = 0.f, a3 = 0.f;
  if (end > off) {
    float den = 0.f;
    for (int i = off; i < end; ++i) den += __expf(logit[eord[i]]);
    float rden = 1.0f / den;
    for (int i = off; i < end; ++i) {
      int e = eord[i];
      float al = __expf(logit[e]) * rden;
      int s = esrc[e];
      ushort4 v = *(const ushort4*)(A + (size_t)s * K2D + t * 4);
      a0 += al * bf2f(v.x);
      a1 += al * bf2f(v.y);
      a2 += al * bf2f(v.z);
      a3 += al * bf2f(v.w);
    }
  }
  ushort4 o;
  o.x = f2bf(a0); o.y = f2bf(a1); o.z = f2bf(a2); o.w = f2bf(a3);
  *(ushort4*)(A + (size_t)n * K2D + DIM + t * 4) = o;
}

// ---- K4: node MLP GEMM (bf16, UNCHANGED round-0 verified), tile 64 x 512 ----
__global__ __launch_bounds__(256, 2) void k_node_gemm(
    const unsigned short* __restrict__ A,
    const unsigned short* __restrict__ Wt_hn, const unsigned short* __restrict__ Wt_on,
    const float* __restrict__ b_hn, const float* __restrict__ b_on,
    float* __restrict__ out) {
  const int t = threadIdx.x;
  const int half = blockIdx.x;
  const int m0 = blockIdx.y * 64;
  const unsigned short* Wt = (m0 < NHN) ? Wt_hn : Wt_on;
  const float* bias = (m0 < NHN) ? b_hn : b_on;
  const int n0 = half * 512;

  __shared__ __align__(16) unsigned short sA[64 * 64];
  __shared__ __align__(16) unsigned short sB[512 * 64];

  const int row0 = t >> 3;
  const int cg = ((t & 7) ^ (row0 & 7)) * 8;
  const unsigned short* pA0 = A + (size_t)(m0 + row0) * K2D + cg;
  const unsigned short* pB0 = Wt + (size_t)(n0 + row0) * K2D + cg;
  unsigned short* lA0 = sA + t * 8;
  unsigned short* lA1 = sA + (256 + t) * 8;
  unsigned short* lB0 = sB + t * 8;

  const int lane = t & 63, wid = t >> 6;
  const int quad = lane >> 4, l16 = lane & 15;

  f32x4 acc[4][8];
#pragma unroll
  for (int a = 0; a < 4; ++a)
#pragma unroll
    for (int b = 0; b < 8; ++b) acc[a][b] = (f32x4){0.f, 0.f, 0.f, 0.f};

#pragma unroll 1
  for (int k0 = 0; k0 < K2D; k0 += 64) {
    async16(pA0 + k0, lA0);
    async16(pA0 + (size_t)32 * K2D + k0, lA1);
#pragma unroll
    for (int p = 0; p < 16; ++p)
      async16(pB0 + (size_t)p * (32 * K2D) + k0, lB0 + p * 2048);
    __syncthreads();
#pragma unroll 1
    for (int kk = 0; kk < 2; ++kk) {
      const int pc = ((kk * 4 + quad) ^ (l16 & 7)) * 8;
      s16x8 af[4], bfr[8];
#pragma unroll
      for (int mt = 0; mt < 4; ++mt)
        af[mt] = *(const s16x8*)(sA + (mt * 16 + l16) * 64 + pc);
#pragma unroll
      for (int nt = 0; nt < 8; ++nt)
        bfr[nt] = *(const s16x8*)(sB + (wid * 128 + nt * 16 + l16) * 64 + pc);
#pragma unroll
      for (int mt = 0; mt < 4; ++mt)
#pragma unroll
        for (int nt = 0; nt < 8; ++nt)
          acc[mt][nt] = __builtin_amdgcn_mfma_f32_16x16x32_bf16(af[mt], bfr[nt], acc[mt][nt], 0, 0, 0);
    }
    __syncthreads();
  }
#pragma unroll
  for (int nt = 0; nt < 8; ++nt) {
    int jl = wid * 128 + nt * 16 + l16;
    float bj = bias[n0 + jl];
    int j = n0 + jl;
#pragma unroll
    for (int mt = 0; mt < 4; ++mt)
#pragma unroll
      for (int r = 0; r < 4; ++r) {
        float v = acc[mt][nt][r] + bj;
        v = v > 0.f ? v : 0.f;
        int m = m0 + mt * 16 + quad * 4 + r;
        out[(size_t)m * DIM + j] = v;
      }
  }
}

// ---- workspace layout (bytes) — UNCHANGED ENVELOPE (ends 88801536) ----
//   A_node : 0          .. 67108864   [16384][2048] bf16
//            (fp8 A8 scratch lives in bytes [n*4096+2048, n*4096+3072) of
//             each row — the z-half — consumed by K1 before K3 rewrites it)
//   Wt8    : 67108864   .. 73400320   3 x [1024][2048] fp8 (x64: hh, oo, ho)
//   WtN    : 73400320   .. 81788928   2 x [1024][2048] bf16 (hn, on)
//   logit  : 88080384   .. 88342528   [65536] f32
//   counts : 88342528   .. 88408064   [16384] i32
//   offsets: 88408064   .. 88473856   [16385] i32 (+pad)
//   cursor : 88473856   .. 88539392   [16384] i32
//   eord   : 88539392   .. 88801536   [65536] i32
extern "C" void kernel_launch(void* const* d_in, const int* in_sizes, int n_in,
                              void* d_out, int out_size, void* d_ws, size_t ws_size,
                              hipStream_t stream) {
  const float* n_f  = (const float*)d_in[0];
  const float* W_hh = (const float*)d_in[1];
  const float* b_hh = (const float*)d_in[2];
  const float* W_oo = (const float*)d_in[3];
  const float* b_oo = (const float*)d_in[4];
  const float* W_ho = (const float*)d_in[5];
  const float* b_ho = (const float*)d_in[6];
  const float* W_a  = (const float*)d_in[7];
  // d_in[8] = b_a : dropped (uniform shift cancels in segment softmax)
  const float* W_hn = (const float*)d_in[9];
  const float* b_hn = (const float*)d_in[10];
  const float* W_on = (const float*)d_in[11];
  const float* b_on = (const float*)d_in[12];
  const int* esrc = (const int*)d_in[13];
  const int* edst = (const int*)d_in[14];
  float* out = (float*)d_out;

  char* ws = (char*)d_ws;
  unsigned short* A_node = (unsigned short*)(ws);
  unsigned char* A8      = (unsigned char*)(ws + 2048);      // row stride 4096 B (z-half scratch)
  unsigned char* Wt8     = (unsigned char*)(ws + 67108864);
  unsigned short* WtN    = (unsigned short*)(ws + 73400320);
  float* logit  = (float*)(ws + 88080384);
  int* counts   = (int*)(ws + 88342528);
  int* offsets  = (int*)(ws + 88408064);
  int* cursor   = (int*)(ws + 88473856);
  int* eord     = (int*)(ws + 88539392);

  hipMemsetAsync(ws + 88080384, 0, 262144 + 65536, stream);

  k_cast_nf<<<16384, 256, 0, stream>>>(n_f, A_node, A8);
  k_transpose<<<5 * 2048, 256, 0, stream>>>(W_hh, W_oo, W_ho, W_hn, W_on, Wt8, WtN);
  k_edge_logit<<<dim3(4, E_TOT / 128), 256, 0, stream>>>(A8, Wt8, b_hh, b_oo, b_ho, W_a, esrc, edst, logit);
  k_count<<<E_TOT / 256, 256, 0, stream>>>(edst, counts);
  k_scan<<<1, 1024, 0, stream>>>(counts, offsets, cursor);
  k_fill<<<E_TOT / 256, 256, 0, stream>>>(edst, cursor, eord);
  k_aggregate<<<N_NODES, 256, 0, stream>>>(offsets, eord, logit, esrc, A_node);
  k_node_gemm<<<dim3(2, N_NODES / 64), 256, 0, stream>>>(
      A_node, WtN, WtN + 2097152, b_hn, b_on, out);
}